// Round 1
// baseline (1147.563 us; speedup 1.0000x reference)
//
#include <hip/hip_runtime.h>
#include <hip/hip_bf16.h>
#include <math.h>

// Problem constants
#define Bq  512
#define Lq  41
#define Vq  4
#define Dq  64
#define NLq 3
#define DIq 128
#define Nq  16
#define DTRq 4
#define Kq  4
#define NSq 3
#define H1q 384
#define H2q 16
#define FLATq (Lq*Dq)   // 2624

// ---------------------------------------------------------------------------
// init: X[s][b][l][d] = embedding[input_ids[b][l]][d]  for all 3 stacks
// ---------------------------------------------------------------------------
__global__ __launch_bounds__(256) void init_kernel(const int* __restrict__ ids,
                                                   const float* __restrict__ emb,
                                                   float* __restrict__ X) {
    int idx = blockIdx.x * 256 + threadIdx.x;
    const int total = NSq * Bq * Lq * Dq;
    if (idx < total) {
        int d  = idx & (Dq - 1);
        int t  = idx >> 6;           // s*B*L + b*L + l
        int bl = t % (Bq * Lq);      // b*L + l  (same for every stack)
        int id = ids[bl];
        X[idx] = emb[id * Dq + d];
    }
}

// ---------------------------------------------------------------------------
// One mamba block for one (stack, batch) pair. 256 threads.
// ---------------------------------------------------------------------------
__global__ __launch_bounds__(256) void layer_kernel(
    float* __restrict__ X,                 // [NS][B][L][D] residual stream (in/out)
    const float* __restrict__ in_proj,     // [NS][NL][D][2*DI]
    const float* __restrict__ conv_w,      // [NS][NL][DI][1][K]
    const float* __restrict__ conv_b,      // [NS][NL][DI]
    const float* __restrict__ x_proj,      // [NS][NL][DI][DTR+2N]
    const float* __restrict__ dt_w,        // [NS][NL][DTR][DI]
    const float* __restrict__ dt_b,        // [NS][NL][DI]
    const float* __restrict__ A_log,       // [NS][NL][DI][N]
    const float* __restrict__ Dp,          // [NS][NL][DI]
    const float* __restrict__ out_proj,    // [NS][NL][DI][D]
    const float* __restrict__ norm_w,      // [NS][NL][D]
    int layer)
{
    const int b   = blockIdx.x;
    const int s   = blockIdx.y;
    const int tid = threadIdx.x;
    const int sl  = s * NLq + layer;

    __shared__ float xn [Lq][Dq];          // 10.25 KB  normalized input
    __shared__ float u  [Lq][DIq];         // 20.5 KB   u (pre/post conv+silu)
    __shared__ float rs [Lq][DIq];         // 20.5 KB   silu(res)
    __shared__ float dbl[Lq][DTRq + 2*Nq]; // 5.77 KB   x_proj output
    __shared__ float dtl[Lq][DIq];         // 20.5 KB   dt, later reused as z

    float* xrow = X + ((size_t)(s * Bq + b)) * (Lq * Dq);

    const int wave = tid >> 6;
    const int lane = tid & 63;

    // ---- Step A: RMSNorm over D=64 (one wave per row) --------------------
    {
        const float* nw = norm_w + (size_t)sl * Dq;
        float nwv = nw[lane];
        for (int l = wave; l < Lq; l += 4) {
            float v  = xrow[l * Dq + lane];
            float ss = v * v;
            #pragma unroll
            for (int off = 32; off; off >>= 1) ss += __shfl_xor(ss, off, 64);
            float scale = rsqrtf(ss * (1.0f / Dq) + 1e-5f);
            xn[l][lane] = v * scale * nwv;
        }
    }
    __syncthreads();

    // ---- Step B: in_proj GEMM [41,64]@[64,256]; thread = output column ---
    {
        const float* W = in_proj + (size_t)sl * (Dq * 2 * DIq);
        const int j = tid;
        float wreg[Dq];
        #pragma unroll
        for (int d = 0; d < Dq; ++d) wreg[d] = W[d * (2*DIq) + j];
        const bool isU = (j < DIq);
        const int  jj  = isU ? j : j - DIq;
        for (int l = 0; l < Lq; ++l) {
            float acc = 0.f;
            #pragma unroll
            for (int d = 0; d < Dq; ++d) acc += xn[l][d] * wreg[d];
            if (isU) u[l][jj] = acc;
            else     rs[l][jj] = acc / (1.f + __expf(-acc));   // silu(res)
        }
    }
    __syncthreads();

    // ---- Step C: depthwise causal conv (K=4) + bias + silu, in place -----
    {
        const float* cw = conv_w + (size_t)sl * (DIq * Kq);
        const float* cb = conv_b + (size_t)sl * DIq;
        float tmp[21];
        int cnt = 0;
        for (int idx = tid; idx < Lq * DIq; idx += 256) {
            int l = idx >> 7, d = idx & (DIq - 1);
            float a = 0.f;
            #pragma unroll
            for (int k = 0; k < Kq; ++k) {
                int ls = l - (Kq - 1) + k;
                float uv = (ls >= 0) ? u[ls][d] : 0.f;
                a += uv * cw[d * Kq + k];
            }
            tmp[cnt++] = a + cb[d];
        }
        __syncthreads();
        cnt = 0;
        for (int idx = tid; idx < Lq * DIq; idx += 256) {
            int l = idx >> 7, d = idx & (DIq - 1);
            float a = tmp[cnt++];
            u[l][d] = a / (1.f + __expf(-a));
        }
    }
    __syncthreads();

    // ---- Step D: dbl = u @ x_proj  [41,128]@[128,36] ---------------------
    {
        const float* xp = x_proj + (size_t)sl * (DIq * (DTRq + 2*Nq));
        for (int idx = tid; idx < Lq * 36; idx += 256) {
            int l = idx / 36, c = idx - l * 36;
            float acc = 0.f;
            #pragma unroll 4
            for (int d = 0; d < DIq; ++d) acc += u[l][d] * xp[d * 36 + c];
            dbl[l][c] = acc;
        }
    }
    __syncthreads();

    // ---- Step E: dt = softplus(dbl[:, :4] @ dt_w + dt_b) -----------------
    {
        const float* dw = dt_w + (size_t)sl * (DTRq * DIq);
        const float* db = dt_b + (size_t)sl * DIq;
        for (int idx = tid; idx < Lq * DIq; idx += 256) {
            int l = idx >> 7, d = idx & (DIq - 1);
            float acc = db[d];
            #pragma unroll
            for (int r = 0; r < DTRq; ++r) acc += dbl[l][r] * dw[r * DIq + d];
            // numerically stable softplus: max(x,0) + log1p(exp(-|x|))
            dtl[l][d] = fmaxf(acc, 0.f) + log1pf(__expf(-fabsf(acc)));
        }
    }
    __syncthreads();

    // ---- Step F: selective scan; 2 threads per channel d, 8 states each --
    {
        const float* al  = A_log + (size_t)sl * (DIq * Nq);
        const float* dpw = Dp    + (size_t)sl * DIq;
        const int d    = tid >> 1;
        const int half = tid & 1;
        const int n0   = half * 8;
        float A[8], h[8];
        #pragma unroll
        for (int n = 0; n < 8; ++n) {
            A[n] = -__expf(al[d * Nq + n0 + n]);
            h[n] = 0.f;
        }
        const float dpd = dpw[d];
        for (int l = 0; l < Lq; ++l) {
            float dt_ = dtl[l][d];
            float u_  = u[l][d];
            float y   = 0.f;
            #pragma unroll
            for (int n = 0; n < 8; ++n) {
                float Bn = dbl[l][DTRq + n0 + n];
                float Cn = dbl[l][DTRq + Nq + n0 + n];
                float dA = __expf(dt_ * A[n]);
                h[n] = dA * h[n] + dt_ * Bn * u_;
                y += h[n] * Cn;
            }
            y += __shfl_xor(y, 1, 64);           // pair-sum over the two halves
            if (half == 0) {
                float yf = y + u_ * dpd;
                dtl[l][d] = yf * rs[l][d];       // z = (y + u*Dp) * silu(res)
            }
        }
    }
    __syncthreads();

    // ---- Step G: residual out GEMM  X += z[41,128] @ op[128,64] ----------
    {
        const float* op = out_proj + (size_t)sl * (DIq * Dq);
        const int j  = tid & 63;
        const int lg = tid >> 6;
        for (int l = lg; l < Lq; l += 4) {
            float acc = 0.f;
            #pragma unroll 4
            for (int d = 0; d < DIq; ++d) acc += dtl[l][d] * op[d * Dq + j];
            xrow[l * Dq + j] += acc;
        }
    }
}

// ---------------------------------------------------------------------------
// head_fuse: per-b, rmsnorm each (s,l) row, softmax(fusion_w)-weighted sum
// over stacks, write Flat[b][l*64+d].
// ---------------------------------------------------------------------------
__global__ __launch_bounds__(256) void head_fuse(const float* __restrict__ X,
                                                 const float* __restrict__ norm_f_w,
                                                 const float* __restrict__ fusion_w,
                                                 float* __restrict__ Flat) {
    const int b    = blockIdx.x;
    const int tid  = threadIdx.x;
    const int wave = tid >> 6, lane = tid & 63;

    float fw0 = fusion_w[0], fw1 = fusion_w[1], fw2 = fusion_w[2];
    float m  = fmaxf(fw0, fmaxf(fw1, fw2));
    float e0 = __expf(fw0 - m), e1 = __expf(fw1 - m), e2 = __expf(fw2 - m);
    float inv = 1.f / (e0 + e1 + e2);
    float w[NSq] = {e0 * inv, e1 * inv, e2 * inv};
    float nf = norm_f_w[lane];

    for (int l = wave; l < Lq; l += 4) {
        float acc = 0.f;
        #pragma unroll
        for (int s = 0; s < NSq; ++s) {
            float v  = X[(((size_t)s * Bq + b) * Lq + l) * Dq + lane];
            float ss = v * v;
            #pragma unroll
            for (int off = 32; off; off >>= 1) ss += __shfl_xor(ss, off, 64);
            acc += w[s] * v * rsqrtf(ss * (1.0f / Dq) + 1e-5f);
        }
        Flat[(size_t)b * FLATq + l * Dq + lane] = acc * nf;
    }
}

// ---------------------------------------------------------------------------
// head_gemm1: H1p[kc][512][384] partials of Flat[512,2624] @ W1[2624,384]
// grid (8 row-tiles, 6 col-tiles, 8 k-chunks of 328); 64x64 tile, 4x4/thread
// ---------------------------------------------------------------------------
__global__ __launch_bounds__(256) void head_gemm1(const float* __restrict__ Aq,
                                                  const float* __restrict__ W1,
                                                  float* __restrict__ H1p) {
    const int rt = blockIdx.x, ct = blockIdx.y, kc = blockIdx.z;
    const int tid = threadIdx.x;
    const int tx = tid & 15, ty = tid >> 4;
    __shared__ float As[64][Lq];   // [row][k]   41 floats per row
    __shared__ float Ws[Lq][64];   // [k][col]
    float acc[4][4] = {};
    const int r0 = rt * 64, c0 = ct * 64;

    for (int st = 0; st < 8; ++st) {
        const int k0 = kc * 328 + st * Lq;
        __syncthreads();
        for (int idx = tid; idx < 64 * Lq; idx += 256) {
            int r = idx / Lq, k = idx - r * Lq;
            As[r][k] = Aq[(size_t)(r0 + r) * FLATq + k0 + k];
        }
        for (int idx = tid; idx < Lq * 64; idx += 256) {
            int k = idx >> 6, c = idx & 63;
            Ws[k][c] = W1[(size_t)(k0 + k) * H1q + c0 + c];
        }
        __syncthreads();
        for (int kk = 0; kk < Lq; ++kk) {
            float a[4], w[4];
            #pragma unroll
            for (int i = 0; i < 4; ++i) a[i] = As[ty * 4 + i][kk];
            #pragma unroll
            for (int j = 0; j < 4; ++j) w[j] = Ws[kk][tx * 4 + j];
            #pragma unroll
            for (int i = 0; i < 4; ++i)
                #pragma unroll
                for (int j = 0; j < 4; ++j) acc[i][j] += a[i] * w[j];
        }
    }
    #pragma unroll
    for (int i = 0; i < 4; ++i)
        #pragma unroll
        for (int j = 0; j < 4; ++j)
            H1p[((size_t)kc * Bq + (r0 + ty * 4 + i)) * H1q + (c0 + tx * 4 + j)] = acc[i][j];
}

// ---------------------------------------------------------------------------
// head_final: sum partials + bias + relu -> h1; h2 = relu(h1@W2+b2);
// logit = h2@W3+b3; out = sigmoid(logit). One block per b.
// ---------------------------------------------------------------------------
__global__ __launch_bounds__(256) void head_final(const float* __restrict__ H1p,
                                                  const float* __restrict__ b1,
                                                  const float* __restrict__ W2,
                                                  const float* __restrict__ b2,
                                                  const float* __restrict__ W3,
                                                  const float* __restrict__ b3,
                                                  float* __restrict__ out) {
    const int b = blockIdx.x, tid = threadIdx.x;
    __shared__ float h1[H1q];
    __shared__ float h2[H2q];
    for (int j = tid; j < H1q; j += 256) {
        float acc = b1[j];
        #pragma unroll
        for (int z = 0; z < 8; ++z) acc += H1p[((size_t)z * Bq + b) * H1q + j];
        h1[j] = fmaxf(acc, 0.f);
    }
    __syncthreads();
    // h2: 16 outputs; 16 groups of 16 threads each
    {
        const int g = tid >> 4, t = tid & 15;
        float acc = 0.f;
        for (int k = t; k < H1q; k += 16) acc += h1[k] * W2[k * H2q + g];
        #pragma unroll
        for (int off = 8; off; off >>= 1) acc += __shfl_xor(acc, off, 64);
        if (t == 0) h2[g] = fmaxf(acc + b2[g], 0.f);
    }
    __syncthreads();
    if (tid == 0) {
        float z = b3[0];
        #pragma unroll
        for (int k = 0; k < H2q; ++k) z += h2[k] * W3[k];
        out[b] = 1.f / (1.f + __expf(-z));
    }
}

// ---------------------------------------------------------------------------
extern "C" void kernel_launch(void* const* d_in, const int* in_sizes, int n_in,
                              void* d_out, int out_size, void* d_ws, size_t ws_size,
                              hipStream_t stream) {
    const int*   ids      = (const int*)  d_in[0];
    const float* emb      = (const float*)d_in[1];
    const float* in_proj  = (const float*)d_in[2];
    const float* conv_w   = (const float*)d_in[3];
    const float* conv_b   = (const float*)d_in[4];
    const float* x_proj   = (const float*)d_in[5];
    const float* dt_w     = (const float*)d_in[6];
    const float* dt_b     = (const float*)d_in[7];
    const float* A_log    = (const float*)d_in[8];
    const float* Dp       = (const float*)d_in[9];
    const float* out_proj = (const float*)d_in[10];
    const float* norm_w   = (const float*)d_in[11];
    const float* norm_f_w = (const float*)d_in[12];
    const float* fusion_w = (const float*)d_in[13];
    const float* W1       = (const float*)d_in[14];
    const float* b1       = (const float*)d_in[15];
    const float* W2       = (const float*)d_in[16];
    const float* b2       = (const float*)d_in[17];
    const float* W3       = (const float*)d_in[18];
    const float* b3       = (const float*)d_in[19];
    float* out = (float*)d_out;

    // workspace layout (floats):
    //   [0, 4030464)            X  (3*512*41*64)    -- later reused as H1p (needs 1572864)
    //   [4030464, 5373952)      Flat (512*2624)
    float* X    = (float*)d_ws;
    float* Flat = X + (size_t)NSq * Bq * Lq * Dq;
    float* H1p  = X;   // alias: X is dead once head_fuse has produced Flat

    const int total = NSq * Bq * Lq * Dq;
    hipLaunchKernelGGL(init_kernel, dim3((total + 255) / 256), dim3(256), 0, stream,
                       ids, emb, X);

    for (int layer = 0; layer < NLq; ++layer) {
        hipLaunchKernelGGL(layer_kernel, dim3(Bq, NSq), dim3(256), 0, stream,
                           X, in_proj, conv_w, conv_b, x_proj, dt_w, dt_b,
                           A_log, Dp, out_proj, norm_w, layer);
    }

    hipLaunchKernelGGL(head_fuse, dim3(Bq), dim3(256), 0, stream,
                       X, norm_f_w, fusion_w, Flat);

    hipLaunchKernelGGL(head_gemm1, dim3(8, 6, 8), dim3(256), 0, stream,
                       Flat, W1, H1p);

    hipLaunchKernelGGL(head_final, dim3(Bq), dim3(256), 0, stream,
                       H1p, b1, W2, b2, W3, b3, out);
}

// Round 2
// 691.152 us; speedup vs baseline: 1.6604x; 1.6604x over previous
//
#include <hip/hip_runtime.h>
#include <hip/hip_bf16.h>
#include <math.h>

// Problem constants
#define Bq  512
#define Lq  41
#define Vq  4
#define Dq  64
#define NLq 3
#define DIq 128
#define Nq  16
#define DTRq 4
#define Kq  4
#define NSq 3
#define H1q 384
#define H2q 16
#define FLATq (Lq*Dq)   // 2624
#define UROW 44         // padded row stride for transposed u (float4-aligned)

// ---------------------------------------------------------------------------
// init: X[s][b][l][d] = embedding[input_ids[b][l]][d]  for all 3 stacks
// ---------------------------------------------------------------------------
__global__ __launch_bounds__(256) void init_kernel(const int* __restrict__ ids,
                                                   const float* __restrict__ emb,
                                                   float* __restrict__ X) {
    int idx = blockIdx.x * 256 + threadIdx.x;
    const int total = NSq * Bq * Lq * Dq;
    if (idx < total) {
        int d  = idx & (Dq - 1);
        int t  = idx >> 6;           // s*B*L + b*L + l
        int bl = t % (Bq * Lq);      // b*L + l  (same for every stack)
        int id = ids[bl];
        X[idx] = emb[id * Dq + d];
    }
}

// ---------------------------------------------------------------------------
// One mamba block for one (stack, batch) pair. 256 threads, 3 blocks/CU.
// LDS: xn4 10.25K + u_t 22K + rsb 10.25K + dbl4 5.77K = 48.3K
// ---------------------------------------------------------------------------
__global__ __launch_bounds__(256, 3) void layer_kernel(
    float* __restrict__ X,                 // [NS][B][L][D] residual stream (in/out)
    const float* __restrict__ in_proj,     // [NS][NL][D][2*DI]
    const float* __restrict__ conv_w,      // [NS][NL][DI][1][K]
    const float* __restrict__ conv_b,      // [NS][NL][DI]
    const float* __restrict__ x_proj,      // [NS][NL][DI][DTR+2N]
    const float* __restrict__ dt_w,        // [NS][NL][DTR][DI]
    const float* __restrict__ dt_b,        // [NS][NL][DI]
    const float* __restrict__ A_log,       // [NS][NL][DI][N]
    const float* __restrict__ Dp,          // [NS][NL][DI]
    const float* __restrict__ out_proj,    // [NS][NL][DI][D]
    const float* __restrict__ norm_w,      // [NS][NL][D]
    int layer)
{
    const int b   = blockIdx.x;
    const int s   = blockIdx.y;
    const int tid = threadIdx.x;
    const int sl  = s * NLq + layer;

    __shared__ float4 xn4[Lq][Dq/4];              // normalized input, row-major
    __shared__ float  u_t[DIq][UROW];             // u TRANSPOSED [d][l]; later z
    __shared__ __hip_bfloat16 rsb[Lq][DIq];       // silu(res), bf16
    __shared__ float4 dbl4[Lq][9];                // x_proj output (36 f32/row)

    float* xnf  = (float*)xn4;
    float* dblf = (float*)dbl4;

    float* xrow = X + ((size_t)(s * Bq + b)) * (Lq * Dq);

    const int wave = tid >> 6;
    const int lane = tid & 63;

    // ---- Preload in_proj column for step B (64 floats -> 16 float4) ------
    const float* W = in_proj + (size_t)sl * (Dq * 2 * DIq);
    float4 wreg[16];
    #pragma unroll
    for (int q = 0; q < 16; ++q) {
        wreg[q].x = W[(q*4+0) * (2*DIq) + tid];
        wreg[q].y = W[(q*4+1) * (2*DIq) + tid];
        wreg[q].z = W[(q*4+2) * (2*DIq) + tid];
        wreg[q].w = W[(q*4+3) * (2*DIq) + tid];
    }

    // ---- Step A: RMSNorm; rows grouped to match step G (residual in regs)
    float res[12];
    {
        const float nwv = norm_w[(size_t)sl * Dq + lane];
        #pragma unroll
        for (int k = 0; k < 3; ++k) {
            #pragma unroll
            for (int i = 0; i < 4; ++i) {
                int l = wave * 4 + k * 16 + i;
                if (l < Lq) {
                    float v  = xrow[l * Dq + lane];
                    res[k*4+i] = v;
                    float ss = v * v;
                    #pragma unroll
                    for (int off = 32; off; off >>= 1) ss += __shfl_xor(ss, off, 64);
                    float scale = rsqrtf(ss * (1.0f / Dq) + 1e-5f);
                    xnf[l * Dq + lane] = v * scale * nwv;
                }
            }
        }
    }
    __syncthreads();

    // ---- Step B: in_proj GEMM [41,64]@[64,256]; thread = output column ---
    {
        const int j   = tid;
        const bool isU = (j < DIq);
        const int  jj  = isU ? j : j - DIq;
        for (int l = 0; l < Lq; ++l) {
            float4 a4 = {0.f, 0.f, 0.f, 0.f};
            #pragma unroll
            for (int q = 0; q < 16; ++q) {
                float4 xv = xn4[l][q];            // broadcast b128
                a4.x = fmaf(xv.x, wreg[q].x, a4.x);
                a4.y = fmaf(xv.y, wreg[q].y, a4.y);
                a4.z = fmaf(xv.z, wreg[q].z, a4.z);
                a4.w = fmaf(xv.w, wreg[q].w, a4.w);
            }
            float acc = (a4.x + a4.y) + (a4.z + a4.w);
            if (isU) u_t[jj][l] = acc;            // transposed write
            else     rsb[l][jj] = __float2bfloat16(acc / (1.f + __expf(-acc)));
        }
    }
    __syncthreads();

    // ---- Step C: depthwise causal conv (K=4) + bias + silu, in place -----
    // thread pair (2d, 2d+1): half0 rows 0..20, half1 rows 21..40.
    {
        const float* cw = conv_w + (size_t)sl * (DIq * Kq);
        const float* cb = conv_b + (size_t)sl * DIq;
        const int d    = tid >> 1;
        const int half = tid & 1;
        const float c0 = cw[d*Kq+0], c1 = cw[d*Kq+1], c2 = cw[d*Kq+2], c3 = cw[d*Kq+3];
        const float cbv = cb[d];
        float w0 = 0.f, w1 = 0.f, w2 = 0.f;
        if (half) { w0 = u_t[d][18]; w1 = u_t[d][19]; w2 = u_t[d][20]; }
        const int base = half ? 21 : 0;
        #pragma unroll
        for (int i = 0; i < 21; ++i) {
            int l = base + i;
            if (l < Lq) {
                float cur = u_t[d][l];
                float a = fmaf(w0, c0, fmaf(w1, c1, fmaf(w2, c2, fmaf(cur, c3, cbv))));
                u_t[d][l] = a / (1.f + __expf(-a));
                w0 = w1; w1 = w2; w2 = cur;
            }
        }
    }
    __syncthreads();

    // ---- Step D: dbl = u @ x_proj  [41,128]@[128,36] ---------------------
    // task = (c, l0-block of 4 rows); 36*11 = 396 tasks
    {
        const float* xp = x_proj + (size_t)sl * (DIq * (DTRq + 2*Nq));
        for (int t = tid; t < 36 * 11; t += 256) {
            const int lb = t / 36;          // 0..10
            const int c  = t - lb * 36;
            const int l0 = lb * 4;
            float4 acc = {0.f, 0.f, 0.f, 0.f};
            for (int d = 0; d < DIq; ++d) {
                float  xv = xp[d * 36 + c];
                float4 uq = *(const float4*)&u_t[d][l0];   // 4 rows, broadcast
                acc.x = fmaf(uq.x, xv, acc.x);
                acc.y = fmaf(uq.y, xv, acc.y);
                acc.z = fmaf(uq.z, xv, acc.z);
                acc.w = fmaf(uq.w, xv, acc.w);
            }
            dblf[(l0+0)*36 + c] = acc.x;
            if (l0+1 < Lq) dblf[(l0+1)*36 + c] = acc.y;
            if (l0+2 < Lq) dblf[(l0+2)*36 + c] = acc.z;
            if (l0+3 < Lq) dblf[(l0+3)*36 + c] = acc.w;
        }
    }
    __syncthreads();

    // ---- Step F: scan with inline dt; 2 threads/channel, 8 states each ---
    // z = (y + u*Dp)*silu(res) overwrites u_t[d][l] in place (pair-local).
    {
        const int d    = tid >> 1;
        const int half = tid & 1;
        const int n0   = half * 8;
        const float* al = A_log + (size_t)sl * (DIq * Nq) + d * Nq + n0;
        float A[8], h[8];
        #pragma unroll
        for (int n = 0; n < 8; ++n) { A[n] = -__expf(al[n]); h[n] = 0.f; }
        const float* dw = dt_w + (size_t)sl * (DTRq * DIq);
        const float dw0 = dw[0*DIq+d], dw1 = dw[1*DIq+d], dw2 = dw[2*DIq+d], dw3 = dw[3*DIq+d];
        const float dbv = dt_b[(size_t)sl * DIq + d];
        const float dpd = Dp[(size_t)sl * DIq + d];
        const int bsel = 1 + 2*half, csel = 5 + 2*half;
        for (int l = 0; l < Lq; ++l) {
            float4 q0 = dbl4[l][0];
            float x  = fmaf(q0.x, dw0, fmaf(q0.y, dw1, fmaf(q0.z, dw2, fmaf(q0.w, dw3, dbv))));
            float dt_ = fmaxf(x, 0.f) + __logf(1.f + __expf(-fabsf(x)));   // softplus
            float u_  = u_t[d][l];
            float rsv = __bfloat162float(rsb[l][d]);
            float4 B0 = dbl4[l][bsel], B1 = dbl4[l][bsel+1];
            float4 C0 = dbl4[l][csel], C1 = dbl4[l][csel+1];
            float dtu = dt_ * u_;
            float y = 0.f;
            float Bv[8] = {B0.x,B0.y,B0.z,B0.w,B1.x,B1.y,B1.z,B1.w};
            float Cv[8] = {C0.x,C0.y,C0.z,C0.w,C1.x,C1.y,C1.z,C1.w};
            #pragma unroll
            for (int n = 0; n < 8; ++n) {
                float dA = __expf(dt_ * A[n]);
                h[n] = fmaf(dA, h[n], Bv[n] * dtu);
                y    = fmaf(h[n], Cv[n], y);
            }
            y += __shfl_xor(y, 1, 64);            // pair-sum over halves
            if (!half) u_t[d][l] = fmaf(u_, dpd, y) * rsv;   // z in place
        }
    }
    __syncthreads();

    // ---- Step G: residual out GEMM  X += z[41,128] @ op[128,64] ----------
    {
        const float* op = out_proj + (size_t)sl * (DIq * Dq);
        const int j  = tid & 63;
        const int lg = tid >> 6;
        const int l0a = lg * 4, l0b = lg * 4 + 16, l0c = lg * 4 + 32;
        float4 acc0 = {0,0,0,0}, acc1 = {0,0,0,0}, acc2 = {0,0,0,0};
        for (int d = 0; d < DIq; ++d) {
            float w = op[d * Dq + j];
            {
                float4 z = *(const float4*)&u_t[d][l0a];
                acc0.x = fmaf(z.x, w, acc0.x); acc0.y = fmaf(z.y, w, acc0.y);
                acc0.z = fmaf(z.z, w, acc0.z); acc0.w = fmaf(z.w, w, acc0.w);
            }
            {
                float4 z = *(const float4*)&u_t[d][l0b];
                acc1.x = fmaf(z.x, w, acc1.x); acc1.y = fmaf(z.y, w, acc1.y);
                acc1.z = fmaf(z.z, w, acc1.z); acc1.w = fmaf(z.w, w, acc1.w);
            }
            if (l0c < Lq) {
                float4 z = *(const float4*)&u_t[d][l0c];
                acc2.x = fmaf(z.x, w, acc2.x); acc2.y = fmaf(z.y, w, acc2.y);
                acc2.z = fmaf(z.z, w, acc2.z); acc2.w = fmaf(z.w, w, acc2.w);
            }
        }
        const float a0[4] = {acc0.x, acc0.y, acc0.z, acc0.w};
        const float a1[4] = {acc1.x, acc1.y, acc1.z, acc1.w};
        const float a2[4] = {acc2.x, acc2.y, acc2.z, acc2.w};
        #pragma unroll
        for (int i = 0; i < 4; ++i) {
            int l = l0a + i;
            if (l < Lq) xrow[l * Dq + j] = res[0*4+i] + a0[i];
        }
        #pragma unroll
        for (int i = 0; i < 4; ++i) {
            int l = l0b + i;
            if (l < Lq) xrow[l * Dq + j] = res[1*4+i] + a1[i];
        }
        #pragma unroll
        for (int i = 0; i < 4; ++i) {
            int l = l0c + i;
            if (l < Lq) xrow[l * Dq + j] = res[2*4+i] + a2[i];
        }
    }
}

// ---------------------------------------------------------------------------
// head_fuse: per-b, rmsnorm each (s,l) row, softmax(fusion_w)-weighted sum
// ---------------------------------------------------------------------------
__global__ __launch_bounds__(256) void head_fuse(const float* __restrict__ X,
                                                 const float* __restrict__ norm_f_w,
                                                 const float* __restrict__ fusion_w,
                                                 float* __restrict__ Flat) {
    const int b    = blockIdx.x;
    const int tid  = threadIdx.x;
    const int wave = tid >> 6, lane = tid & 63;

    float fw0 = fusion_w[0], fw1 = fusion_w[1], fw2 = fusion_w[2];
    float m  = fmaxf(fw0, fmaxf(fw1, fw2));
    float e0 = __expf(fw0 - m), e1 = __expf(fw1 - m), e2 = __expf(fw2 - m);
    float inv = 1.f / (e0 + e1 + e2);
    float w[NSq] = {e0 * inv, e1 * inv, e2 * inv};
    float nf = norm_f_w[lane];

    for (int l = wave; l < Lq; l += 4) {
        float acc = 0.f;
        #pragma unroll
        for (int s = 0; s < NSq; ++s) {
            float v  = X[(((size_t)s * Bq + b) * Lq + l) * Dq + lane];
            float ss = v * v;
            #pragma unroll
            for (int off = 32; off; off >>= 1) ss += __shfl_xor(ss, off, 64);
            acc += w[s] * v * rsqrtf(ss * (1.0f / Dq) + 1e-5f);
        }
        Flat[(size_t)b * FLATq + l * Dq + lane] = acc * nf;
    }
}

// ---------------------------------------------------------------------------
// head_gemm1: H1p[kc][512][384] partials of Flat[512,2624] @ W1[2624,384]
// ---------------------------------------------------------------------------
__global__ __launch_bounds__(256) void head_gemm1(const float* __restrict__ Aq,
                                                  const float* __restrict__ W1,
                                                  float* __restrict__ H1p) {
    const int rt = blockIdx.x, ct = blockIdx.y, kc = blockIdx.z;
    const int tid = threadIdx.x;
    const int tx = tid & 15, ty = tid >> 4;
    __shared__ float As[64][Lq];
    __shared__ float Ws[Lq][64];
    float acc[4][4] = {};
    const int r0 = rt * 64, c0 = ct * 64;

    for (int st = 0; st < 8; ++st) {
        const int k0 = kc * 328 + st * Lq;
        __syncthreads();
        for (int idx = tid; idx < 64 * Lq; idx += 256) {
            int r = idx / Lq, k = idx - r * Lq;
            As[r][k] = Aq[(size_t)(r0 + r) * FLATq + k0 + k];
        }
        for (int idx = tid; idx < Lq * 64; idx += 256) {
            int k = idx >> 6, c = idx & 63;
            Ws[k][c] = W1[(size_t)(k0 + k) * H1q + c0 + c];
        }
        __syncthreads();
        for (int kk = 0; kk < Lq; ++kk) {
            float a[4], w[4];
            #pragma unroll
            for (int i = 0; i < 4; ++i) a[i] = As[ty * 4 + i][kk];
            #pragma unroll
            for (int j = 0; j < 4; ++j) w[j] = Ws[kk][tx * 4 + j];
            #pragma unroll
            for (int i = 0; i < 4; ++i)
                #pragma unroll
                for (int j = 0; j < 4; ++j) acc[i][j] += a[i] * w[j];
        }
    }
    #pragma unroll
    for (int i = 0; i < 4; ++i)
        #pragma unroll
        for (int j = 0; j < 4; ++j)
            H1p[((size_t)kc * Bq + (r0 + ty * 4 + i)) * H1q + (c0 + tx * 4 + j)] = acc[i][j];
}

// ---------------------------------------------------------------------------
// head_final
// ---------------------------------------------------------------------------
__global__ __launch_bounds__(256) void head_final(const float* __restrict__ H1p,
                                                  const float* __restrict__ b1,
                                                  const float* __restrict__ W2,
                                                  const float* __restrict__ b2,
                                                  const float* __restrict__ W3,
                                                  const float* __restrict__ b3,
                                                  float* __restrict__ out) {
    const int b = blockIdx.x, tid = threadIdx.x;
    __shared__ float h1[H1q];
    __shared__ float h2[H2q];
    for (int j = tid; j < H1q; j += 256) {
        float acc = b1[j];
        #pragma unroll
        for (int z = 0; z < 8; ++z) acc += H1p[((size_t)z * Bq + b) * H1q + j];
        h1[j] = fmaxf(acc, 0.f);
    }
    __syncthreads();
    {
        const int g = tid >> 4, t = tid & 15;
        float acc = 0.f;
        for (int k = t; k < H1q; k += 16) acc += h1[k] * W2[k * H2q + g];
        #pragma unroll
        for (int off = 8; off; off >>= 1) acc += __shfl_xor(acc, off, 64);
        if (t == 0) h2[g] = fmaxf(acc + b2[g], 0.f);
    }
    __syncthreads();
    if (tid == 0) {
        float z = b3[0];
        #pragma unroll
        for (int k = 0; k < H2q; ++k) z += h2[k] * W3[k];
        out[b] = 1.f / (1.f + __expf(-z));
    }
}

// ---------------------------------------------------------------------------
extern "C" void kernel_launch(void* const* d_in, const int* in_sizes, int n_in,
                              void* d_out, int out_size, void* d_ws, size_t ws_size,
                              hipStream_t stream) {
    const int*   ids      = (const int*)  d_in[0];
    const float* emb      = (const float*)d_in[1];
    const float* in_proj  = (const float*)d_in[2];
    const float* conv_w   = (const float*)d_in[3];
    const float* conv_b   = (const float*)d_in[4];
    const float* x_proj   = (const float*)d_in[5];
    const float* dt_w     = (const float*)d_in[6];
    const float* dt_b     = (const float*)d_in[7];
    const float* A_log    = (const float*)d_in[8];
    const float* Dp       = (const float*)d_in[9];
    const float* out_proj = (const float*)d_in[10];
    const float* norm_w   = (const float*)d_in[11];
    const float* norm_f_w = (const float*)d_in[12];
    const float* fusion_w = (const float*)d_in[13];
    const float* W1       = (const float*)d_in[14];
    const float* b1       = (const float*)d_in[15];
    const float* W2       = (const float*)d_in[16];
    const float* b2       = (const float*)d_in[17];
    const float* W3       = (const float*)d_in[18];
    const float* b3       = (const float*)d_in[19];
    float* out = (float*)d_out;

    float* X    = (float*)d_ws;
    float* Flat = X + (size_t)NSq * Bq * Lq * Dq;
    float* H1p  = X;   // alias: X dead once head_fuse has produced Flat

    const int total = NSq * Bq * Lq * Dq;
    hipLaunchKernelGGL(init_kernel, dim3((total + 255) / 256), dim3(256), 0, stream,
                       ids, emb, X);

    for (int layer = 0; layer < NLq; ++layer) {
        hipLaunchKernelGGL(layer_kernel, dim3(Bq, NSq), dim3(256), 0, stream,
                           X, in_proj, conv_w, conv_b, x_proj, dt_w, dt_b,
                           A_log, Dp, out_proj, norm_w, layer);
    }

    hipLaunchKernelGGL(head_fuse, dim3(Bq), dim3(256), 0, stream,
                       X, norm_f_w, fusion_w, Flat);

    hipLaunchKernelGGL(head_gemm1, dim3(8, 6, 8), dim3(256), 0, stream,
                       Flat, W1, H1p);

    hipLaunchKernelGGL(head_final, dim3(Bq), dim3(256), 0, stream,
                       H1p, b1, W2, b2, W3, b3, out);
}

// Round 3
// 362.923 us; speedup vs baseline: 3.1620x; 1.9044x over previous
//
#include <hip/hip_runtime.h>
#include <hip/hip_bf16.h>
#include <math.h>

// Problem constants
#define Bq  512
#define Lq  41
#define Vq  4
#define Dq  64
#define NLq 3
#define DIq 128
#define Nq  16
#define DTRq 4
#define Kq  4
#define NSq 3
#define H1q 384
#define H2q 16
#define FLATq (Lq*Dq)   // 2624

typedef __attribute__((ext_vector_type(8))) short frag8;   // 8 bf16 (4 VGPRs)
typedef __attribute__((ext_vector_type(4))) float f32x4;

__device__ __forceinline__ float b2f(unsigned short u) {
    union { float f; unsigned int i; } v; v.i = ((unsigned int)u) << 16; return v.f;
}
__device__ __forceinline__ unsigned short f2b(float f) {
    union { float f; unsigned int i; } v; v.f = f;
    unsigned int x = v.i;
    unsigned int r = (x + 0x7fffu + ((x >> 16) & 1u)) >> 16;
    return (unsigned short)r;
}

// ---------------------------------------------------------------------------
// init: X[s][b][l][d] = embedding[input_ids[b][l]][d]
// ---------------------------------------------------------------------------
__global__ __launch_bounds__(256) void init_kernel(const int* __restrict__ ids,
                                                   const float* __restrict__ emb,
                                                   float* __restrict__ X) {
    int idx = blockIdx.x * 256 + threadIdx.x;
    const int total = NSq * Bq * Lq * Dq;
    if (idx < total) {
        int d  = idx & (Dq - 1);
        int t  = idx >> 6;
        int bl = t % (Bq * Lq);
        int id = ids[bl];
        X[idx] = emb[id * Dq + d];
    }
}

// ---------------------------------------------------------------------------
// prep_small: bf16-convert + transpose the per-layer weights into [n][k]:
//   Wb_in [9][256][64], xp_b [9][48][128] (cols>=36 zero), op_b [9][64][128]
// ---------------------------------------------------------------------------
__global__ __launch_bounds__(256) void prep_small(const float* __restrict__ in_proj,
                                                  const float* __restrict__ x_proj,
                                                  const float* __restrict__ out_proj,
                                                  unsigned short* __restrict__ Wb_in,
                                                  unsigned short* __restrict__ xp_b,
                                                  unsigned short* __restrict__ op_b) {
    int idx = blockIdx.x * 256 + threadIdx.x;
    if (idx < 9*256*64) {
        int sl = idx >> 14, rem = idx & 16383;
        int n = rem >> 6, k = rem & 63;
        Wb_in[idx] = f2b(in_proj[(size_t)sl*16384 + k*256 + n]);
    } else if (idx < 9*256*64 + 9*48*128) {
        int i2 = idx - 9*256*64;
        int sl = i2 / 6144, rem = i2 % 6144;
        int c = rem >> 7, k = rem & 127;
        float v = (c < 36) ? x_proj[(size_t)sl*(128*36) + k*36 + c] : 0.f;
        xp_b[i2] = f2b(v);
    } else if (idx < 9*256*64 + 9*48*128 + 9*64*128) {
        int i3 = idx - (9*256*64 + 9*48*128);
        int sl = i3 >> 13, rem = i3 & 8191;
        int n = rem >> 7, k = rem & 127;
        op_b[i3] = f2b(out_proj[(size_t)sl*8192 + k*64 + n]);
    }
}

// ---------------------------------------------------------------------------
// transpose_w1: W1 [2624][384] fp32 -> W1b [384][2624] bf16 (tiled 64x64)
// ---------------------------------------------------------------------------
__global__ __launch_bounds__(256) void transpose_w1(const float* __restrict__ W1,
                                                    unsigned short* __restrict__ W1b) {
    __shared__ float t[64][65];
    const int k0 = blockIdx.x * 64, n0 = blockIdx.y * 64;
    for (int idx = threadIdx.x; idx < 4096; idx += 256) {
        int kr = idx >> 6, nc = idx & 63;
        t[kr][nc] = W1[(size_t)(k0 + kr) * H1q + n0 + nc];
    }
    __syncthreads();
    for (int idx = threadIdx.x; idx < 4096; idx += 256) {
        int nr = idx >> 6, kc = idx & 63;
        W1b[(size_t)(n0 + nr) * FLATq + k0 + kc] = f2b(t[kc][nr]);
    }
}

// ---------------------------------------------------------------------------
// layer_kernel: one mamba block per (s,b). 256 threads, 4 blocks/CU.
// MFMA 16x16x32 bf16 for the 3 GEMMs; fp32 scan.
// LDS: xn 6.75K + u 13.06K + rs 10.9K + dbl 7.69K = 38.1 KB
// ---------------------------------------------------------------------------
__global__ __launch_bounds__(256, 4) void layer_kernel(
    float* __restrict__ X,
    const unsigned short* __restrict__ Wb_in,   // [9][256][64]
    const float* __restrict__ conv_w,
    const float* __restrict__ conv_b,
    const unsigned short* __restrict__ xp_b,    // [9][48][128]
    const float* __restrict__ dt_w,
    const float* __restrict__ dt_b,
    const float* __restrict__ A_log,
    const float* __restrict__ Dp,
    const unsigned short* __restrict__ op_b,    // [9][64][128]
    const float* __restrict__ norm_w,
    int layer)
{
    const int b = blockIdx.x, s = blockIdx.y, tid = threadIdx.x;
    const int sl = s * NLq + layer;
    const int wave = tid >> 6, lane = tid & 63;
    const int nl = lane & 15, quad = lane >> 4;

    __shared__ unsigned short xn_lb[48][72];    // bf16 normalized input (M-pad 48)
    __shared__ unsigned short u_lb [48][136];   // bf16 u, then z in place
    __shared__ unsigned short rs_lb[41][136];   // bf16 silu(res)
    __shared__ float dbl_s[41][48];             // fp32 x_proj output (cols>=36 pad)

    float* xrow = X + ((size_t)(s * Bq + b)) * (Lq * Dq);

    // ---- A: rmsnorm -> xn bf16; pad rows zeroed --------------------------
    {
        const float nwv = norm_w[(size_t)sl * Dq + lane];
        for (int l = wave; l < 48; l += 4) {
            if (l < Lq) {
                float v  = xrow[l * Dq + lane];
                float ss = v * v;
                #pragma unroll
                for (int off = 32; off; off >>= 1) ss += __shfl_xor(ss, off, 64);
                float scale = rsqrtf(ss * (1.0f / Dq) + 1e-5f);
                xn_lb[l][lane] = f2b(v * scale * nwv);
            } else {
                xn_lb[l][lane] = 0;
            }
        }
    }
    __syncthreads();

    // ---- B: [48,64]@[64,256] MFMA; cols<128 -> u, cols>=128 -> silu -> rs
    {
        #pragma unroll
        for (int t = 0; t < 12; ++t) {
            const int id = wave * 12 + t;
            const int mt = id >> 4, nt = id & 15;
            const unsigned short* Wp = Wb_in + ((size_t)(sl * 256 + nt * 16 + nl)) * 64 + quad * 8;
            frag8 a0 = *(const frag8*)&xn_lb[mt * 16 + nl][quad * 8];
            frag8 a1 = *(const frag8*)&xn_lb[mt * 16 + nl][32 + quad * 8];
            frag8 b0 = *(const frag8*)&Wp[0];
            frag8 b1 = *(const frag8*)&Wp[32];
            f32x4 c = {0.f, 0.f, 0.f, 0.f};
            c = __builtin_amdgcn_mfma_f32_16x16x32_bf16(a0, b0, c, 0, 0, 0);
            c = __builtin_amdgcn_mfma_f32_16x16x32_bf16(a1, b1, c, 0, 0, 0);
            const int col = nt * 16 + nl;
            const int r0 = mt * 16 + quad * 4;
            if (col < DIq) {
                #pragma unroll
                for (int r = 0; r < 4; ++r) u_lb[r0 + r][col] = f2b(c[r]);
            } else {
                const int d = col - DIq;
                #pragma unroll
                for (int r = 0; r < 4; ++r) {
                    int row = r0 + r;
                    if (row < Lq) {
                        float v = c[r];
                        rs_lb[row][d] = f2b(v / (1.f + __expf(-v)));
                    }
                }
            }
        }
    }
    __syncthreads();

    // ---- C: depthwise causal conv (K=4) + bias + silu, in place ----------
    {
        const float* cw = conv_w + (size_t)sl * (DIq * Kq);
        const int d = tid >> 1, half = tid & 1;
        const float c0 = cw[d*4+0], c1 = cw[d*4+1], c2 = cw[d*4+2], c3 = cw[d*4+3];
        const float cbv = conv_b[(size_t)sl * DIq + d];
        float w0 = 0.f, w1 = 0.f, w2 = 0.f;
        if (half) { w0 = b2f(u_lb[18][d]); w1 = b2f(u_lb[19][d]); w2 = b2f(u_lb[20][d]); }
        const int base = half ? 21 : 0;
        const int cnt  = half ? 20 : 21;
        for (int i = 0; i < cnt; ++i) {
            int l = base + i;
            float cur = b2f(u_lb[l][d]);
            float a = fmaf(w0, c0, fmaf(w1, c1, fmaf(w2, c2, fmaf(cur, c3, cbv))));
            u_lb[l][d] = f2b(a / (1.f + __expf(-a)));
            w0 = w1; w1 = w2; w2 = cur;
        }
    }
    __syncthreads();

    // ---- D: dbl = u[48,128] @ xp[128,48] MFMA ----------------------------
    {
        for (int t = wave; t < 9; t += 4) {
            const int mt = t / 3, ct = t % 3;
            f32x4 c = {0.f, 0.f, 0.f, 0.f};
            #pragma unroll
            for (int kt = 0; kt < 4; ++kt) {
                frag8 a  = *(const frag8*)&u_lb[mt * 16 + nl][kt * 32 + quad * 8];
                frag8 bb = *(const frag8*)&xp_b[((size_t)(sl * 48 + ct * 16 + nl)) * 128 + kt * 32 + quad * 8];
                c = __builtin_amdgcn_mfma_f32_16x16x32_bf16(a, bb, c, 0, 0, 0);
            }
            const int col = ct * 16 + nl, r0 = mt * 16 + quad * 4;
            #pragma unroll
            for (int r = 0; r < 4; ++r) {
                int row = r0 + r;
                if (row < Lq) dbl_s[row][col] = c[r];
            }
        }
    }
    __syncthreads();

    // ---- F: selective scan, fp32 state; z -> u_lb in place (bf16) --------
    {
        const int d = tid >> 1, half = tid & 1;
        const float* al = A_log + (size_t)sl * (DIq * Nq) + d * Nq + half * 8;
        float A[8], h[8];
        #pragma unroll
        for (int n = 0; n < 8; ++n) { A[n] = -__expf(al[n]); h[n] = 0.f; }
        const float* dw = dt_w + (size_t)sl * (DTRq * DIq);
        const float dw0 = dw[d], dw1 = dw[DIq + d], dw2 = dw[2*DIq + d], dw3 = dw[3*DIq + d];
        const float dbv = dt_b[(size_t)sl * DIq + d];
        const float dpd = Dp[(size_t)sl * DIq + d];
        for (int l = 0; l < Lq; ++l) {
            float4 q0 = *(const float4*)&dbl_s[l][0];
            float x  = fmaf(q0.x, dw0, fmaf(q0.y, dw1, fmaf(q0.z, dw2, fmaf(q0.w, dw3, dbv))));
            float dt_ = fmaxf(x, 0.f) + __logf(1.f + __expf(-fabsf(x)));
            float u_  = b2f(u_lb[l][d]);
            float rsv = b2f(rs_lb[l][d]);
            float4 B0 = *(const float4*)&dbl_s[l][4  + half * 8];
            float4 B1 = *(const float4*)&dbl_s[l][8  + half * 8];
            float4 C0 = *(const float4*)&dbl_s[l][20 + half * 8];
            float4 C1 = *(const float4*)&dbl_s[l][24 + half * 8];
            float dtu = dt_ * u_;
            float Bv[8] = {B0.x,B0.y,B0.z,B0.w,B1.x,B1.y,B1.z,B1.w};
            float Cv[8] = {C0.x,C0.y,C0.z,C0.w,C1.x,C1.y,C1.z,C1.w};
            float y = 0.f;
            #pragma unroll
            for (int n = 0; n < 8; ++n) {
                float dA = __expf(dt_ * A[n]);
                h[n] = fmaf(dA, h[n], Bv[n] * dtu);
                y    = fmaf(h[n], Cv[n], y);
            }
            y += __shfl_xor(y, 1, 64);
            if (!half) u_lb[l][d] = f2b(fmaf(u_, dpd, y) * rsv);
        }
    }
    __syncthreads();

    // ---- G: X += z[48,128] @ op[128,64] MFMA -----------------------------
    {
        const int ntG = wave;
        for (int mt = 0; mt < 3; ++mt) {
            f32x4 c = {0.f, 0.f, 0.f, 0.f};
            #pragma unroll
            for (int kt = 0; kt < 4; ++kt) {
                frag8 a  = *(const frag8*)&u_lb[mt * 16 + nl][kt * 32 + quad * 8];
                frag8 bb = *(const frag8*)&op_b[((size_t)(sl * 64 + ntG * 16 + nl)) * 128 + kt * 32 + quad * 8];
                c = __builtin_amdgcn_mfma_f32_16x16x32_bf16(a, bb, c, 0, 0, 0);
            }
            const int j = ntG * 16 + nl, r0 = mt * 16 + quad * 4;
            #pragma unroll
            for (int r = 0; r < 4; ++r) {
                int row = r0 + r;
                if (row < Lq) xrow[row * Dq + j] += c[r];
            }
        }
    }
}

// ---------------------------------------------------------------------------
// head_fuse: rmsnorm each (s,l) row, softmax-weighted stack sum -> Flat bf16
// ---------------------------------------------------------------------------
__global__ __launch_bounds__(256) void head_fuse(const float* __restrict__ X,
                                                 const float* __restrict__ norm_f_w,
                                                 const float* __restrict__ fusion_w,
                                                 unsigned short* __restrict__ Flat_b) {
    const int b    = blockIdx.x;
    const int tid  = threadIdx.x;
    const int wave = tid >> 6, lane = tid & 63;

    float fw0 = fusion_w[0], fw1 = fusion_w[1], fw2 = fusion_w[2];
    float m  = fmaxf(fw0, fmaxf(fw1, fw2));
    float e0 = __expf(fw0 - m), e1 = __expf(fw1 - m), e2 = __expf(fw2 - m);
    float inv = 1.f / (e0 + e1 + e2);
    float w[NSq] = {e0 * inv, e1 * inv, e2 * inv};
    float nf = norm_f_w[lane];

    for (int l = wave; l < Lq; l += 4) {
        float acc = 0.f;
        #pragma unroll
        for (int s = 0; s < NSq; ++s) {
            float v  = X[(((size_t)s * Bq + b) * Lq + l) * Dq + lane];
            float ss = v * v;
            #pragma unroll
            for (int off = 32; off; off >>= 1) ss += __shfl_xor(ss, off, 64);
            acc += w[s] * v * rsqrtf(ss * (1.0f / Dq) + 1e-5f);
        }
        Flat_b[(size_t)b * FLATq + l * Dq + lane] = f2b(acc * nf);
    }
}

// ---------------------------------------------------------------------------
// head_gemm1: H1[512,384] = Flat[512,2624] @ W1[2624,384], bf16 MFMA.
// grid (32 m-tiles, 6); each wave owns one 16x16 tile over full K.
// ---------------------------------------------------------------------------
__global__ __launch_bounds__(256) void head_gemm1(const unsigned short* __restrict__ Flat_b,
                                                  const unsigned short* __restrict__ W1b,
                                                  float* __restrict__ H1) {
    const int tid = threadIdx.x;
    const int wave = tid >> 6, lane = tid & 63;
    const int nl = lane & 15, quad = lane >> 4;
    const int mt = blockIdx.x;
    const int nt = blockIdx.y * 4 + wave;

    const unsigned short* Arow = Flat_b + (size_t)(mt * 16 + nl) * FLATq + quad * 8;
    const unsigned short* Brow = W1b    + (size_t)(nt * 16 + nl) * FLATq + quad * 8;
    f32x4 c = {0.f, 0.f, 0.f, 0.f};
    #pragma unroll 2
    for (int k0 = 0; k0 < FLATq; k0 += 32) {
        frag8 a  = *(const frag8*)(Arow + k0);
        frag8 bb = *(const frag8*)(Brow + k0);
        c = __builtin_amdgcn_mfma_f32_16x16x32_bf16(a, bb, c, 0, 0, 0);
    }
    #pragma unroll
    for (int r = 0; r < 4; ++r)
        H1[(size_t)(mt * 16 + quad * 4 + r) * H1q + nt * 16 + nl] = c[r];
}

// ---------------------------------------------------------------------------
// head_final: h1 = relu(H1 + b1); h2 = relu(h1@W2+b2); sigmoid(h2@W3+b3)
// ---------------------------------------------------------------------------
__global__ __launch_bounds__(256) void head_final(const float* __restrict__ H1,
                                                  const float* __restrict__ b1,
                                                  const float* __restrict__ W2,
                                                  const float* __restrict__ b2,
                                                  const float* __restrict__ W3,
                                                  const float* __restrict__ b3,
                                                  float* __restrict__ out) {
    const int b = blockIdx.x, tid = threadIdx.x;
    __shared__ float h1[H1q];
    __shared__ float h2[H2q];
    for (int j = tid; j < H1q; j += 256)
        h1[j] = fmaxf(H1[(size_t)b * H1q + j] + b1[j], 0.f);
    __syncthreads();
    {
        const int g = tid >> 4, t = tid & 15;
        float acc = 0.f;
        for (int k = t; k < H1q; k += 16) acc += h1[k] * W2[k * H2q + g];
        #pragma unroll
        for (int off = 8; off; off >>= 1) acc += __shfl_xor(acc, off, 64);
        if (t == 0) h2[g] = fmaxf(acc + b2[g], 0.f);
    }
    __syncthreads();
    if (tid == 0) {
        float z = b3[0];
        #pragma unroll
        for (int k = 0; k < H2q; ++k) z += h2[k] * W3[k];
        out[b] = 1.f / (1.f + __expf(-z));
    }
}

// ---------------------------------------------------------------------------
extern "C" void kernel_launch(void* const* d_in, const int* in_sizes, int n_in,
                              void* d_out, int out_size, void* d_ws, size_t ws_size,
                              hipStream_t stream) {
    const int*   ids      = (const int*)  d_in[0];
    const float* emb      = (const float*)d_in[1];
    const float* in_proj  = (const float*)d_in[2];
    const float* conv_w   = (const float*)d_in[3];
    const float* conv_b   = (const float*)d_in[4];
    const float* x_proj   = (const float*)d_in[5];
    const float* dt_w     = (const float*)d_in[6];
    const float* dt_b     = (const float*)d_in[7];
    const float* A_log    = (const float*)d_in[8];
    const float* Dp       = (const float*)d_in[9];
    const float* out_proj = (const float*)d_in[10];
    const float* norm_w   = (const float*)d_in[11];
    const float* norm_f_w = (const float*)d_in[12];
    const float* fusion_w = (const float*)d_in[13];
    const float* W1       = (const float*)d_in[14];
    const float* b1       = (const float*)d_in[15];
    const float* W2       = (const float*)d_in[16];
    const float* b2       = (const float*)d_in[17];
    const float* W3       = (const float*)d_in[18];
    const float* b3       = (const float*)d_in[19];
    float* out = (float*)d_out;

    // workspace layout:
    //   X       fp32  3*512*41*64  = 4,030,464 f   (later aliased by H1 512*384)
    //   Flat_b  bf16  512*2624     = 1,343,488 us
    //   Wb_in   bf16  9*256*64     =   147,456 us
    //   xp_b    bf16  9*48*128     =    55,296 us
    //   op_b    bf16  9*64*128     =    73,728 us
    //   W1b     bf16  384*2624     = 1,007,616 us
    // total 21.38 MB
    float* X = (float*)d_ws;
    unsigned short* Flat_b = (unsigned short*)(X + (size_t)NSq*Bq*Lq*Dq);
    unsigned short* Wb_in  = Flat_b + (size_t)Bq*FLATq;
    unsigned short* xp_b   = Wb_in  + 9*256*64;
    unsigned short* op_b   = xp_b   + 9*48*128;
    unsigned short* W1b    = op_b   + 9*64*128;
    float* H1 = X;   // alias: X dead after head_fuse

    const int prep_total = 9*256*64 + 9*48*128 + 9*64*128;
    hipLaunchKernelGGL(prep_small, dim3((prep_total + 255) / 256), dim3(256), 0, stream,
                       in_proj, x_proj, out_proj, Wb_in, xp_b, op_b);
    hipLaunchKernelGGL(transpose_w1, dim3(FLATq/64, H1q/64), dim3(256), 0, stream,
                       W1, W1b);

    const int total = NSq * Bq * Lq * Dq;
    hipLaunchKernelGGL(init_kernel, dim3((total + 255) / 256), dim3(256), 0, stream,
                       ids, emb, X);

    for (int layer = 0; layer < NLq; ++layer) {
        hipLaunchKernelGGL(layer_kernel, dim3(Bq, NSq), dim3(256), 0, stream,
                           X, Wb_in, conv_w, conv_b, xp_b, dt_w, dt_b,
                           A_log, Dp, op_b, norm_w, layer);
    }

    hipLaunchKernelGGL(head_fuse, dim3(Bq), dim3(256), 0, stream,
                       X, norm_f_w, fusion_w, Flat_b);

    hipLaunchKernelGGL(head_gemm1, dim3(Bq/16, H1q/64), dim3(256), 0, stream,
                       Flat_b, W1b, H1);

    hipLaunchKernelGGL(head_final, dim3(Bq), dim3(256), 0, stream,
                       H1, b1, W2, b2, W3, b3, out);
}